// Round 18
// baseline (168.017 us; speedup 1.0000x reference)
//
#include <hip/hip_runtime.h>
#include <cstdint>
#include <cstddef>

typedef __attribute__((ext_vector_type(8))) short bf16x8;
typedef __attribute__((ext_vector_type(4))) unsigned short u16x4;
typedef __attribute__((ext_vector_type(4))) unsigned u32x4;
typedef __attribute__((ext_vector_type(4))) float f32x4;
typedef unsigned short u16;

#define T_TOT 9728
#define DDIM  2048
#define GHN   256
#define NSEQ  8

__device__ __constant__ int OFFS[NSEQ + 1] = {0, 512, 1536, 3072, 5120, 5760, 6656, 7936, 9728};

__device__ __forceinline__ u16 f2bf(float f) {
  union { float f; unsigned u; } v; v.f = f;
  unsigned r = v.u + 0x7FFFu + ((v.u >> 16) & 1u);
  return (u16)(r >> 16);
}
__device__ __forceinline__ float silu_f(float v) {
  return v / (1.0f + __expf(-v));
}

// Pin a 128-bit value into regs: volatile asm can't be duplicated, so the
// compiler cannot rematerialize the originating load inside later loops.
__device__ __forceinline__ void pin_reg(bf16x8& v) {
  u32x4& u = reinterpret_cast<u32x4&>(v);
  asm volatile("" : "+v"(u));
}

// async global->LDS, 16B per lane, wave-uniform LDS base + lane*16 (m97 pattern)
__device__ __forceinline__ void gload_lds16(const u16* src, u16* dst) {
  __builtin_amdgcn_global_load_lds(
      (__attribute__((address_space(1))) void*)src,
      (__attribute__((address_space(3))) void*)dst,
      16, 0, 0);
}

// ---------------------------------------------------------------------------
// Prep: fp32 [R][C] -> bf16 [C][R]  (transpose + convert), 64x64 tiles
// ---------------------------------------------------------------------------
__global__ __launch_bounds__(256)
void transpose_bf16_k(const float* __restrict__ in, u16* __restrict__ out, int R, int C) {
  __shared__ float tile[64][65];
  const int c0 = blockIdx.x * 64, r0 = blockIdx.y * 64;
  const int tid = threadIdx.x;
  const int lc = tid & 63, lr = tid >> 6;
#pragma unroll
  for (int p = 0; p < 16; ++p) {
    int r = lr + p * 4;
    tile[r][lc] = in[(size_t)(r0 + r) * C + c0 + lc];
  }
  __syncthreads();
#pragma unroll
  for (int p = 0; p < 16; ++p) {
    int c = lr + p * 4;
    out[(size_t)(c0 + c) * R + r0 + lc] = f2bf(tile[lc][c]);
  }
}

// ---------------------------------------------------------------------------
// Kernel A: h = silu(gi @ w1)  (r17-validated).  Grid (2 N-halves fastest,
// 304 token-tiles); unroll-by-2 K-loop with 2-step-ahead gi prefetch;
// double-buffered A, one barrier per K-step.
// h stored PRE-SWIZZLED: element (t,c) at t*256 + ((c>>3)^(t&7))*8 + (c&7).
// ---------------------------------------------------------------------------
__global__ __launch_bounds__(256, 4)
void gemm1_silu(const float* __restrict__ gi, const u16* __restrict__ w1T,
                u16* __restrict__ h) {
  __shared__ u16 A[2][32][72];
  const int tid = threadIdx.x;
  const int lane = tid & 63, wid = tid >> 6;
  const int l15 = lane & 15, l4 = lane >> 4;
  const int t0 = blockIdx.y * 32;
  const int nb = blockIdx.x * 128 + wid * 32;   // wave's 32-col base

  f32x4 acc[2][2] = {};

  // stage roles: two (row, f4-slot) pairs per thread (rows m0 and m0+16)
  const int m0 = tid >> 4, f40 = tid & 15;
  const float* g0 = gi + (size_t)(t0 + m0) * DDIM + f40 * 4;
  const float* g1 = gi + (size_t)(t0 + m0 + 16) * DDIM + f40 * 4;

  // 2-step-ahead prefetch state
  f32x4 pvA0 = *reinterpret_cast<const f32x4*>(g0);
  f32x4 pvA1 = *reinterpret_cast<const f32x4*>(g1);
  f32x4 pvB0 = *reinterpret_cast<const f32x4*>(g0 + 64);
  f32x4 pvB1 = *reinterpret_cast<const f32x4*>(g1 + 64);

  for (int k0 = 0; k0 < DDIM; k0 += 128) {
    // ---- sub-step A: K-slab k0, LDS buffer 0, prefetch k0+128 into pvA ----
    {
      u16x4 b0, b1;
      b0[0] = f2bf(pvA0[0]); b0[1] = f2bf(pvA0[1]); b0[2] = f2bf(pvA0[2]); b0[3] = f2bf(pvA0[3]);
      b1[0] = f2bf(pvA1[0]); b1[1] = f2bf(pvA1[1]); b1[2] = f2bf(pvA1[2]); b1[3] = f2bf(pvA1[3]);
      *reinterpret_cast<u16x4*>(&A[0][m0][f40 * 4]) = b0;
      *reinterpret_cast<u16x4*>(&A[0][m0 + 16][f40 * 4]) = b1;
      if (k0 + 128 < DDIM) {
        pvA0 = *reinterpret_cast<const f32x4*>(g0 + k0 + 128);
        pvA1 = *reinterpret_cast<const f32x4*>(g1 + k0 + 128);
      }
      __syncthreads();  // publishes A[0]
#pragma unroll
      for (int ks = 0; ks < 2; ++ks) {
        bf16x8 af[2], bfr[2];
#pragma unroll
        for (int mi = 0; mi < 2; ++mi)
          af[mi] = *reinterpret_cast<const bf16x8*>(&A[0][mi * 16 + l15][ks * 32 + 8 * l4]);
#pragma unroll
        for (int ni = 0; ni < 2; ++ni)
          bfr[ni] = *reinterpret_cast<const bf16x8*>(
              &w1T[(size_t)(nb + ni * 16 + l15) * DDIM + k0 + ks * 32 + 8 * l4]);
#pragma unroll
        for (int mi = 0; mi < 2; ++mi)
#pragma unroll
          for (int ni = 0; ni < 2; ++ni)
            acc[mi][ni] = __builtin_amdgcn_mfma_f32_16x16x32_bf16(af[mi], bfr[ni], acc[mi][ni], 0, 0, 0);
      }
    }
    // ---- sub-step B: K-slab k0+64, LDS buffer 1, prefetch k0+192 into pvB ----
    {
      u16x4 b0, b1;
      b0[0] = f2bf(pvB0[0]); b0[1] = f2bf(pvB0[1]); b0[2] = f2bf(pvB0[2]); b0[3] = f2bf(pvB0[3]);
      b1[0] = f2bf(pvB1[0]); b1[1] = f2bf(pvB1[1]); b1[2] = f2bf(pvB1[2]); b1[3] = f2bf(pvB1[3]);
      *reinterpret_cast<u16x4*>(&A[1][m0][f40 * 4]) = b0;
      *reinterpret_cast<u16x4*>(&A[1][m0 + 16][f40 * 4]) = b1;
      if (k0 + 192 < DDIM) {
        pvB0 = *reinterpret_cast<const f32x4*>(g0 + k0 + 192);
        pvB1 = *reinterpret_cast<const f32x4*>(g1 + k0 + 192);
      }
      __syncthreads();  // publishes A[1]
#pragma unroll
      for (int ks = 0; ks < 2; ++ks) {
        bf16x8 af[2], bfr[2];
#pragma unroll
        for (int mi = 0; mi < 2; ++mi)
          af[mi] = *reinterpret_cast<const bf16x8*>(&A[1][mi * 16 + l15][ks * 32 + 8 * l4]);
#pragma unroll
        for (int ni = 0; ni < 2; ++ni)
          bfr[ni] = *reinterpret_cast<const bf16x8*>(
              &w1T[(size_t)(nb + ni * 16 + l15) * DDIM + k0 + 64 + ks * 32 + 8 * l4]);
#pragma unroll
        for (int mi = 0; mi < 2; ++mi)
#pragma unroll
          for (int ni = 0; ni < 2; ++ni)
            acc[mi][ni] = __builtin_amdgcn_mfma_f32_16x16x32_bf16(af[mi], bfr[ni], acc[mi][ni], 0, 0, 0);
      }
    }
  }

#pragma unroll
  for (int mi = 0; mi < 2; ++mi)
#pragma unroll
    for (int ni = 0; ni < 2; ++ni)
#pragma unroll
      for (int r = 0; r < 4; ++r) {
        float v = silu_f(acc[mi][ni][r]);
        int token = t0 + mi * 16 + l4 * 4 + r;
        int c = nb + ni * 16 + l15;
        int pos = ((((c >> 3) ^ (token & 7)) << 3) | (c & 7));
        h[(size_t)token * GHN + pos] = f2bf(v);
      }
}

// ---------------------------------------------------------------------------
// Kernel B: fused kern = h@w2+b2 -> 4-tap conv -> silu -> out.
// r15 skeleton (64-token chunks, swapped grid) with Ot REMOVED:
// direct per-lane 4B stores (L2 merges: the block's 4 waves write the 4x32B
// quarters of each 128B line near-simultaneously, and the 64 col-tile sibling
// blocks of a token-group co-run).  ONE barrier per chunk: drains the staging
// vmcnt (issued at chunk top -> full GEMM+conv of flight) and orders the
// H double-buffer swap.  bw pinned; permuted-col shfl conv; b2 in acc init.
// ---------------------------------------------------------------------------
__global__ __launch_bounds__(256, 2)
void gemm2_conv(const u16* __restrict__ h, const u16* __restrict__ w2T,
                const float* __restrict__ b2, const float* __restrict__ x,
                const float* __restrict__ cs, float* __restrict__ out) {
  __shared__ u16 H[2][64 * 256];   // 2 x 32KB double buffer
  const int tid = threadIdx.x;
  const int lane = tid & 63, wid = tid >> 6;
  const int l15 = lane & 15, l4 = lane >> 4;
  const int colwave = blockIdx.x * 128 + wid * 32;   // x = col-tile (fastest)
  const int tg = blockIdx.y;           // y = token-group (256 tokens)

  // permuted original-column base for this lane (ni adds 0/1)
  const int ocol = colwave + 4 * (l15 >> 1) + 2 * (l15 & 1);

  // w2 fragments: load once, then PIN in regs
  bf16x8 bw[8][2];
#pragma unroll
  for (int ks = 0; ks < 8; ++ks)
#pragma unroll
    for (int ni = 0; ni < 2; ++ni)
      bw[ks][ni] = *reinterpret_cast<const bf16x8*>(
          w2T + (size_t)(ocol + ni) * GHN + ks * 32 + l4 * 8);
#pragma unroll
  for (int ks = 0; ks < 8; ++ks)
#pragma unroll
    for (int ni = 0; ni < 2; ++ni)
      pin_reg(bw[ks][ni]);

  float b2v[2];
#pragma unroll
  for (int ni = 0; ni < 2; ++ni) b2v[ni] = b2[ocol + ni];

  const int d = (colwave >> 2) + (l15 >> 1);  // this lane's conv channel
  const int k0t = 2 * (l15 & 1);              // first tap held by this lane
  const int par = lane & 1;

  // prologue: stage chunk 0 into H[0] (linear dest: h is pre-swizzled)
  {
    const u16* hb = h + (size_t)(tg * 4) * 64 * GHN;
#pragma unroll
    for (int p = 0; p < 8; ++p)
      gload_lds16(hb + (size_t)(p * 256 + tid) * 8, &H[0][(p * 256 + tid) * 8]);
  }
  __syncthreads();

  for (int it = 0; it < 4; ++it) {
    const int t0 = (tg * 4 + it) * 64;
    const int cur = it & 1;

    // ---- issue next chunk's staging FIRST: full GEMM+conv of flight ----
    if (it < 3) {
      const u16* hb = h + (size_t)(t0 + 64) * GHN;
#pragma unroll
      for (int p = 0; p < 8; ++p)
        gload_lds16(hb + (size_t)(p * 256 + tid) * 8, &H[cur ^ 1][(p * 256 + tid) * 8]);
    }

    int iseq = 0;
    while (OFFS[iseq + 1] <= t0) ++iseq;   // block-uniform
    const int seq_start = OFFS[iseq];

    // ---- T14: prefetch conv x-inputs (hide under GEMM) ----
    float xw[4][5];
#pragma unroll
    for (int mi = 0; mi < 4; ++mi) {
      const int base = t0 + mi * 16 + l4 * 4;
      const int s0 = base + k0t - 3;
      const float* xr = x + (size_t)s0 * DDIM + d;
      const float* cr = cs + ((size_t)iseq * DDIM + d) * 3 + (s0 - seq_start + 3);
      xw[mi][0] = (s0 >= seq_start) ? xr[0] : cr[0];
      xw[mi][1] = (s0 + 1 >= seq_start) ? xr[DDIM] : cr[1];
      xw[mi][2] = (s0 + 2 >= seq_start) ? xr[2 * DDIM] : cr[2];
      xw[mi][3] = xr[3 * DDIM];  // s0+3 = base+k0t >= t0 >= seq_start always
      xw[mi][4] = xr[4 * DDIM];  // s0+4 <= t0+63 < T always
    }

    // ---- GEMM: 8 ks x (4 A-frag ds_read + 8 MFMA), B pinned, b2 in acc ----
    f32x4 acc[4][2];
#pragma unroll
    for (int mi = 0; mi < 4; ++mi)
#pragma unroll
      for (int ni = 0; ni < 2; ++ni) {
        acc[mi][ni][0] = b2v[ni]; acc[mi][ni][1] = b2v[ni];
        acc[mi][ni][2] = b2v[ni]; acc[mi][ni][3] = b2v[ni];
      }
    const u16* Hb = H[cur];
#pragma unroll
    for (int ks = 0; ks < 8; ++ks) {
#pragma unroll
      for (int mi = 0; mi < 4; ++mi) {
        int m = mi * 16 + l15;
        int g = ks * 4 + l4;
        bf16x8 af = *reinterpret_cast<const bf16x8*>(&Hb[m * 256 + ((g ^ (m & 7)) << 3)]);
#pragma unroll
        for (int ni = 0; ni < 2; ++ni)
          acc[mi][ni] = __builtin_amdgcn_mfma_f32_16x16x32_bf16(af, bw[ks][ni], acc[mi][ni], 0, 0, 0);
      }
    }

    // ---- conv epilogue: FMA + shfl, DIRECT 4B stores (no Ot, no barrier) ----
#pragma unroll
    for (int mi = 0; mi < 4; ++mi) {
      const int base = t0 + mi * 16 + l4 * 4;
#pragma unroll
      for (int r = 0; r < 4; ++r) {
        float partial = acc[mi][0][r] * xw[mi][r] + acc[mi][1][r] * xw[mi][r + 1];
        float tot = partial + __shfl_xor(partial, 1);
        if ((r >> 1) == par)
          out[(size_t)(base + r) * DDIM + d] = silu_f(tot);
      }
    }

    __syncthreads();  // THE barrier: drains staging vmcnt (H[cur^1] ready) and
                      // orders this chunk's H[cur] reads before it+1's writes
  }
}

// ---------------------------------------------------------------------------
// Kernel C: new_conv_state[i][d][m] = x[offs[i+1]-3+m][d]
// ---------------------------------------------------------------------------
__global__ __launch_bounds__(256)
void tail_state(const float* __restrict__ x, float* __restrict__ out2) {
  int idx = blockIdx.x * 256 + threadIdx.x;
  int i = idx / (DDIM * 3);
  int rem = idx - i * (DDIM * 3);
  int d = rem / 3, m = rem - d * 3;
  int token = OFFS[i + 1] - 3 + m;
  out2[idx] = x[(size_t)token * DDIM + d];
}

// ---------------------------------------------------------------------------
extern "C" void kernel_launch(void* const* d_in, const int* in_sizes, int n_in,
                              void* d_out, int out_size, void* d_ws, size_t ws_size,
                              hipStream_t stream) {
  (void)in_sizes; (void)n_in; (void)out_size; (void)ws_size;
  const float* x  = (const float*)d_in[0];
  const float* cs = (const float*)d_in[1];
  const float* gi = (const float*)d_in[2];
  const float* w1 = (const float*)d_in[4];
  const float* w2 = (const float*)d_in[5];
  const float* b2 = (const float*)d_in[6];
  float* out = (float*)d_out;

  char* ws = (char*)d_ws;
  u16* w2T = (u16*)ws;                        // [8192][256] bf16 : 4,194,304 B
  u16* w1T = (u16*)(ws + 4194304);            // [256][2048] bf16 : 1,048,576 B
  u16* h   = (u16*)(ws + 4194304 + 1048576);  // [9728][256] bf16 swizzled : 4,980,736 B

  transpose_bf16_k<<<dim3(8192 / 64, 256 / 64), 256, 0, stream>>>(w2, w2T, GHN, DDIM * 4);
  transpose_bf16_k<<<dim3(256 / 64, 2048 / 64), 256, 0, stream>>>(w1, w1T, DDIM, GHN);
  // grid (2 N-halves fastest, 304 token-tiles): both halves of a tile co-run
  gemm1_silu<<<dim3(2, T_TOT / 32), 256, 0, stream>>>(gi, w1T, h);
  // swapped grid: x = 64 col-tiles (fastest), y = 38 token-groups of 256
  gemm2_conv<<<dim3((DDIM * 4) / 128, T_TOT / 256), 256, 0, stream>>>(h, w2T, b2, x, cs, out);
  tail_state<<<(NSEQ * DDIM * 3) / 256, 256, 0, stream>>>(x, out + (size_t)T_TOT * DDIM);
}

// Round 19
// 159.312 us; speedup vs baseline: 1.0546x; 1.0546x over previous
//
#include <hip/hip_runtime.h>
#include <cstdint>
#include <cstddef>

typedef __attribute__((ext_vector_type(8))) short bf16x8;
typedef __attribute__((ext_vector_type(4))) unsigned short u16x4;
typedef __attribute__((ext_vector_type(4))) unsigned u32x4;
typedef __attribute__((ext_vector_type(4))) float f32x4;
typedef unsigned short u16;

#define T_TOT 9728
#define DDIM  2048
#define GHN   256
#define NSEQ  8

__device__ __constant__ int OFFS[NSEQ + 1] = {0, 512, 1536, 3072, 5120, 5760, 6656, 7936, 9728};

__device__ __forceinline__ u16 f2bf(float f) {
  union { float f; unsigned u; } v; v.f = f;
  unsigned r = v.u + 0x7FFFu + ((v.u >> 16) & 1u);
  return (u16)(r >> 16);
}
__device__ __forceinline__ float silu_f(float v) {
  return v / (1.0f + __expf(-v));
}

// Pin a 128-bit value into regs: volatile asm can't be duplicated, so the
// compiler cannot rematerialize the originating load inside later loops.
__device__ __forceinline__ void pin_reg(bf16x8& v) {
  u32x4& u = reinterpret_cast<u32x4&>(v);
  asm volatile("" : "+v"(u));
}

// async global->LDS, 16B per lane, wave-uniform LDS base + lane*16 (m97 pattern)
__device__ __forceinline__ void gload_lds16(const u16* src, u16* dst) {
  __builtin_amdgcn_global_load_lds(
      (__attribute__((address_space(1))) void*)src,
      (__attribute__((address_space(3))) void*)dst,
      16, 0, 0);
}

// ---------------------------------------------------------------------------
// Prep: fp32 [R][C] -> bf16 [C][R]  (transpose + convert), 64x64 tiles
// ---------------------------------------------------------------------------
__global__ __launch_bounds__(256)
void transpose_bf16_k(const float* __restrict__ in, u16* __restrict__ out, int R, int C) {
  __shared__ float tile[64][65];
  const int c0 = blockIdx.x * 64, r0 = blockIdx.y * 64;
  const int tid = threadIdx.x;
  const int lc = tid & 63, lr = tid >> 6;
#pragma unroll
  for (int p = 0; p < 16; ++p) {
    int r = lr + p * 4;
    tile[r][lc] = in[(size_t)(r0 + r) * C + c0 + lc];
  }
  __syncthreads();
#pragma unroll
  for (int p = 0; p < 16; ++p) {
    int c = lr + p * 4;
    out[(size_t)(c0 + c) * R + r0 + lc] = f2bf(tile[lc][c]);
  }
}

// ---------------------------------------------------------------------------
// Kernel A: h = silu(gi @ w1)  (r17/r18-validated, ~31-33us).  Grid
// (2 N-halves fastest, 304 token-tiles); unroll-by-2 K-loop with 2-step-ahead
// gi prefetch; double-buffered A, one barrier per K-step.
// h stored PRE-SWIZZLED: element (t,c) at t*256 + ((c>>3)^(t&7))*8 + (c&7).
// ---------------------------------------------------------------------------
__global__ __launch_bounds__(256, 4)
void gemm1_silu(const float* __restrict__ gi, const u16* __restrict__ w1T,
                u16* __restrict__ h) {
  __shared__ u16 A[2][32][72];
  const int tid = threadIdx.x;
  const int lane = tid & 63, wid = tid >> 6;
  const int l15 = lane & 15, l4 = lane >> 4;
  const int t0 = blockIdx.y * 32;
  const int nb = blockIdx.x * 128 + wid * 32;   // wave's 32-col base

  f32x4 acc[2][2] = {};

  // stage roles: two (row, f4-slot) pairs per thread (rows m0 and m0+16)
  const int m0 = tid >> 4, f40 = tid & 15;
  const float* g0 = gi + (size_t)(t0 + m0) * DDIM + f40 * 4;
  const float* g1 = gi + (size_t)(t0 + m0 + 16) * DDIM + f40 * 4;

  // 2-step-ahead prefetch state
  f32x4 pvA0 = *reinterpret_cast<const f32x4*>(g0);
  f32x4 pvA1 = *reinterpret_cast<const f32x4*>(g1);
  f32x4 pvB0 = *reinterpret_cast<const f32x4*>(g0 + 64);
  f32x4 pvB1 = *reinterpret_cast<const f32x4*>(g1 + 64);

  for (int k0 = 0; k0 < DDIM; k0 += 128) {
    // ---- sub-step A: K-slab k0, LDS buffer 0, prefetch k0+128 into pvA ----
    {
      u16x4 b0, b1;
      b0[0] = f2bf(pvA0[0]); b0[1] = f2bf(pvA0[1]); b0[2] = f2bf(pvA0[2]); b0[3] = f2bf(pvA0[3]);
      b1[0] = f2bf(pvA1[0]); b1[1] = f2bf(pvA1[1]); b1[2] = f2bf(pvA1[2]); b1[3] = f2bf(pvA1[3]);
      *reinterpret_cast<u16x4*>(&A[0][m0][f40 * 4]) = b0;
      *reinterpret_cast<u16x4*>(&A[0][m0 + 16][f40 * 4]) = b1;
      if (k0 + 128 < DDIM) {
        pvA0 = *reinterpret_cast<const f32x4*>(g0 + k0 + 128);
        pvA1 = *reinterpret_cast<const f32x4*>(g1 + k0 + 128);
      }
      __syncthreads();  // publishes A[0]
#pragma unroll
      for (int ks = 0; ks < 2; ++ks) {
        bf16x8 af[2], bfr[2];
#pragma unroll
        for (int mi = 0; mi < 2; ++mi)
          af[mi] = *reinterpret_cast<const bf16x8*>(&A[0][mi * 16 + l15][ks * 32 + 8 * l4]);
#pragma unroll
        for (int ni = 0; ni < 2; ++ni)
          bfr[ni] = *reinterpret_cast<const bf16x8*>(
              &w1T[(size_t)(nb + ni * 16 + l15) * DDIM + k0 + ks * 32 + 8 * l4]);
#pragma unroll
        for (int mi = 0; mi < 2; ++mi)
#pragma unroll
          for (int ni = 0; ni < 2; ++ni)
            acc[mi][ni] = __builtin_amdgcn_mfma_f32_16x16x32_bf16(af[mi], bfr[ni], acc[mi][ni], 0, 0, 0);
      }
    }
    // ---- sub-step B: K-slab k0+64, LDS buffer 1, prefetch k0+192 into pvB ----
    {
      u16x4 b0, b1;
      b0[0] = f2bf(pvB0[0]); b0[1] = f2bf(pvB0[1]); b0[2] = f2bf(pvB0[2]); b0[3] = f2bf(pvB0[3]);
      b1[0] = f2bf(pvB1[0]); b1[1] = f2bf(pvB1[1]); b1[2] = f2bf(pvB1[2]); b1[3] = f2bf(pvB1[3]);
      *reinterpret_cast<u16x4*>(&A[1][m0][f40 * 4]) = b0;
      *reinterpret_cast<u16x4*>(&A[1][m0 + 16][f40 * 4]) = b1;
      if (k0 + 192 < DDIM) {
        pvB0 = *reinterpret_cast<const f32x4*>(g0 + k0 + 192);
        pvB1 = *reinterpret_cast<const f32x4*>(g1 + k0 + 192);
      }
      __syncthreads();  // publishes A[1]
#pragma unroll
      for (int ks = 0; ks < 2; ++ks) {
        bf16x8 af[2], bfr[2];
#pragma unroll
        for (int mi = 0; mi < 2; ++mi)
          af[mi] = *reinterpret_cast<const bf16x8*>(&A[1][mi * 16 + l15][ks * 32 + 8 * l4]);
#pragma unroll
        for (int ni = 0; ni < 2; ++ni)
          bfr[ni] = *reinterpret_cast<const bf16x8*>(
              &w1T[(size_t)(nb + ni * 16 + l15) * DDIM + k0 + 64 + ks * 32 + 8 * l4]);
#pragma unroll
        for (int mi = 0; mi < 2; ++mi)
#pragma unroll
          for (int ni = 0; ni < 2; ++ni)
            acc[mi][ni] = __builtin_amdgcn_mfma_f32_16x16x32_bf16(af[mi], bfr[ni], acc[mi][ni], 0, 0, 0);
      }
    }
  }

#pragma unroll
  for (int mi = 0; mi < 2; ++mi)
#pragma unroll
    for (int ni = 0; ni < 2; ++ni)
#pragma unroll
      for (int r = 0; r < 4; ++r) {
        float v = silu_f(acc[mi][ni][r]);
        int token = t0 + mi * 16 + l4 * 4 + r;
        int c = nb + ni * 16 + l15;
        int pos = ((((c >> 3) ^ (token & 7)) << 3) | (c & 7));
        h[(size_t)token * GHN + pos] = f2bf(v);
      }
}

// ---------------------------------------------------------------------------
// Kernel B: fused kern = h@w2+b2 -> 4-tap conv -> silu -> out.
// 116.3us-validated artifact (runs 15 & 16), byte-identical: swapped grid
// (x = col-tile fastest for DRAM/L2 locality), 64-token chunks, H[2] double
// buffer with issue-at-top staging, bw pinned, permuted-col shfl conv,
// Ot out-staging, 2 barriers/chunk.
// ---------------------------------------------------------------------------
__global__ __launch_bounds__(256, 2)
void gemm2_conv(const u16* __restrict__ h, const u16* __restrict__ w2T,
                const float* __restrict__ b2, const float* __restrict__ x,
                const float* __restrict__ cs, float* __restrict__ out) {
  __shared__ u16 H[2][64 * 256];   // 2 x 32KB double buffer
  __shared__ float Ot[64 * 33];    // 8.25KB out-staging, pad-33
  const int tid = threadIdx.x;
  const int lane = tid & 63, wid = tid >> 6;
  const int l15 = lane & 15, l4 = lane >> 4;
  const int colwave = blockIdx.x * 128 + wid * 32;   // x = col-tile (fastest)
  const int d0 = blockIdx.x * 32;      // block's 32-channel base
  const int tg = blockIdx.y;           // y = token-group

  // permuted original-column base for this lane (ni adds 0/1)
  const int ocol = colwave + 4 * (l15 >> 1) + 2 * (l15 & 1);

  // w2 fragments: load once, then PIN in regs
  bf16x8 bw[8][2];
#pragma unroll
  for (int ks = 0; ks < 8; ++ks)
#pragma unroll
    for (int ni = 0; ni < 2; ++ni)
      bw[ks][ni] = *reinterpret_cast<const bf16x8*>(
          w2T + (size_t)(ocol + ni) * GHN + ks * 32 + l4 * 8);
#pragma unroll
  for (int ks = 0; ks < 8; ++ks)
#pragma unroll
    for (int ni = 0; ni < 2; ++ni)
      pin_reg(bw[ks][ni]);

  float b2v[2];
#pragma unroll
  for (int ni = 0; ni < 2; ++ni) b2v[ni] = b2[ocol + ni];

  const int d = (colwave >> 2) + (l15 >> 1);  // this lane's conv channel
  const int dloc = wid * 8 + (l15 >> 1);      // channel within block (0..31)
  const int k0t = 2 * (l15 & 1);              // first tap held by this lane
  const int par = lane & 1;

  // prologue: stage chunk 0 into H[0] (linear dest: h is pre-swizzled)
  {
    const u16* hb = h + (size_t)(tg * 4) * 64 * GHN;
#pragma unroll
    for (int p = 0; p < 8; ++p)
      gload_lds16(hb + (size_t)(p * 256 + tid) * 8, &H[0][(p * 256 + tid) * 8]);
  }
  __syncthreads();

  int cur = 0;
  for (int it = 0; it < 4; ++it) {
    const int t0 = (tg * 4 + it) * 64;

    // ---- issue next chunk's staging FIRST: full GEMM+conv to fly ----
    if (it < 3) {
      const u16* hb = h + (size_t)(t0 + 64) * GHN;
#pragma unroll
      for (int p = 0; p < 8; ++p)
        gload_lds16(hb + (size_t)(p * 256 + tid) * 8, &H[cur ^ 1][(p * 256 + tid) * 8]);
    }

    int iseq = 0;
    while (OFFS[iseq + 1] <= t0) ++iseq;   // block-uniform
    const int seq_start = OFFS[iseq];

    // ---- T14: prefetch conv x-inputs (hide under GEMM) ----
    float xw[4][5];
#pragma unroll
    for (int mi = 0; mi < 4; ++mi) {
      const int base = t0 + mi * 16 + l4 * 4;
      const int s0 = base + k0t - 3;
      const float* xr = x + (size_t)s0 * DDIM + d;
      const float* cr = cs + ((size_t)iseq * DDIM + d) * 3 + (s0 - seq_start + 3);
      xw[mi][0] = (s0 >= seq_start) ? xr[0] : cr[0];
      xw[mi][1] = (s0 + 1 >= seq_start) ? xr[DDIM] : cr[1];
      xw[mi][2] = (s0 + 2 >= seq_start) ? xr[2 * DDIM] : cr[2];
      xw[mi][3] = xr[3 * DDIM];  // s0+3 = base+k0t >= t0 >= seq_start always
      xw[mi][4] = xr[4 * DDIM];  // s0+4 <= t0+63 < T always
    }

    // ---- GEMM: 8 ks x (4 A-frag ds_read + 8 MFMA), B pinned, b2 in acc ----
    f32x4 acc[4][2];
#pragma unroll
    for (int mi = 0; mi < 4; ++mi)
#pragma unroll
      for (int ni = 0; ni < 2; ++ni) {
        acc[mi][ni][0] = b2v[ni]; acc[mi][ni][1] = b2v[ni];
        acc[mi][ni][2] = b2v[ni]; acc[mi][ni][3] = b2v[ni];
      }
    const u16* Hb = H[cur];
#pragma unroll
    for (int ks = 0; ks < 8; ++ks) {
#pragma unroll
      for (int mi = 0; mi < 4; ++mi) {
        int m = mi * 16 + l15;
        int g = ks * 4 + l4;
        bf16x8 af = *reinterpret_cast<const bf16x8*>(&Hb[m * 256 + ((g ^ (m & 7)) << 3)]);
#pragma unroll
        for (int ni = 0; ni < 2; ++ni)
          acc[mi][ni] = __builtin_amdgcn_mfma_f32_16x16x32_bf16(af, bw[ks][ni], acc[mi][ni], 0, 0, 0);
      }
    }

    __syncthreads();  // barA: separates prev store's Ot reads from conv writes

    // ---- conv epilogue: pure FMA + shfl (x already in regs) -> Ot ----
#pragma unroll
    for (int mi = 0; mi < 4; ++mi) {
#pragma unroll
      for (int r = 0; r < 4; ++r) {
        float partial = acc[mi][0][r] * xw[mi][r] + acc[mi][1][r] * xw[mi][r + 1];
        float tot = partial + __shfl_xor(partial, 1);
        if ((r >> 1) == par)
          Ot[(mi * 16 + l4 * 4 + r) * 33 + dloc] = silu_f(tot);
      }
    }

    __syncthreads();  // barB: Ot complete; vmcnt drain -> H[cur^1] ready

    // ---- coalesced out-store: 4 threads = one dense 128B token row ----
    {
      const int trow = tid >> 2, tq = tid & 3;
      f32x4 o0 = *reinterpret_cast<const f32x4*>(&Ot[trow * 33 + tq * 8]);
      f32x4 o1 = *reinterpret_cast<const f32x4*>(&Ot[trow * 33 + tq * 8 + 4]);
      float* op = out + (size_t)(t0 + trow) * DDIM + d0 + tq * 8;
      *reinterpret_cast<f32x4*>(op) = o0;
      *reinterpret_cast<f32x4*>(op + 4) = o1;
    }
    cur ^= 1;
  }
}

// ---------------------------------------------------------------------------
// Kernel C: new_conv_state[i][d][m] = x[offs[i+1]-3+m][d]
// ---------------------------------------------------------------------------
__global__ __launch_bounds__(256)
void tail_state(const float* __restrict__ x, float* __restrict__ out2) {
  int idx = blockIdx.x * 256 + threadIdx.x;
  int i = idx / (DDIM * 3);
  int rem = idx - i * (DDIM * 3);
  int d = rem / 3, m = rem - d * 3;
  int token = OFFS[i + 1] - 3 + m;
  out2[idx] = x[(size_t)token * DDIM + d];
}

// ---------------------------------------------------------------------------
extern "C" void kernel_launch(void* const* d_in, const int* in_sizes, int n_in,
                              void* d_out, int out_size, void* d_ws, size_t ws_size,
                              hipStream_t stream) {
  (void)in_sizes; (void)n_in; (void)out_size; (void)ws_size;
  const float* x  = (const float*)d_in[0];
  const float* cs = (const float*)d_in[1];
  const float* gi = (const float*)d_in[2];
  const float* w1 = (const float*)d_in[4];
  const float* w2 = (const float*)d_in[5];
  const float* b2 = (const float*)d_in[6];
  float* out = (float*)d_out;

  char* ws = (char*)d_ws;
  u16* w2T = (u16*)ws;                        // [8192][256] bf16 : 4,194,304 B
  u16* w1T = (u16*)(ws + 4194304);            // [256][2048] bf16 : 1,048,576 B
  u16* h   = (u16*)(ws + 4194304 + 1048576);  // [9728][256] bf16 swizzled : 4,980,736 B

  transpose_bf16_k<<<dim3(8192 / 64, 256 / 64), 256, 0, stream>>>(w2, w2T, GHN, DDIM * 4);
  transpose_bf16_k<<<dim3(256 / 64, 2048 / 64), 256, 0, stream>>>(w1, w1T, DDIM, GHN);
  // grid (2 N-halves fastest, 304 token-tiles): both halves of a tile co-run
  gemm1_silu<<<dim3(2, T_TOT / 32), 256, 0, stream>>>(gi, w1T, h);
  // swapped grid: x = 64 col-tiles (fastest), y = 38 token-groups of 256
  gemm2_conv<<<dim3((DDIM * 4) / 128, T_TOT / 256), 256, 0, stream>>>(h, w2T, b2, x, cs, out);
  tail_state<<<(NSEQ * DDIM * 3) / 256, 256, 0, stream>>>(x, out + (size_t)T_TOT * DDIM);
}